// Round 11
// baseline (521.822 us; speedup 1.0000x reference)
//
#include <hip/hip_runtime.h>
#include <math.h>

// Problem constants
static constexpr int BB   = 256;   // batch
static constexpr int NN   = 128;   // nodes
static constexpr int LL   = 2048;  // protein length
static constexpr int NF   = 75;
static constexpr int AC   = 3;
static constexpr int HID  = 256;
static constexpr int DIM  = 128;
static constexpr int NHEAD= 8;
static constexpr int FPD  = 679;
static constexpr int FPDP = 704;   // FPD padded to multiple of 32
static constexpr int NWORD= 8600;
static constexpr int NWP  = 8704;  // NWORD padded to 68*128
static constexpr int KB   = 768;   // AV row stride (3*256)

typedef __attribute__((ext_vector_type(8))) _Float16 f16x8;
typedef __attribute__((ext_vector_type(2))) _Float16 h2v;
typedef __attribute__((ext_vector_type(4))) float f32x4;
typedef unsigned int u32;
typedef unsigned short u16;

__device__ __forceinline__ u16 f2h(float x) {
    _Float16 h = (_Float16)x;       // RNE
    return *(u16*)&h;
}
// saturating fp32->fp16 (avoid inf from rare tail values)
__device__ __forceinline__ u16 f2h_sat(float x) {
    x = fminf(fmaxf(x, -65000.f), 65000.f);
    _Float16 h = (_Float16)x;
    return *(u16*)&h;
}
__device__ __forceinline__ float h2f(u16 x) {
    return (float)(*(_Float16*)&x);
}

// fp16-carried intermediates with large range are stored scaled by 1/16.
static constexpr float SC   = 0.0625f;
static constexpr float USC  = 16.0f;

// ---------------------------------------------------------------------------
// prep: A fp32 -> fp16, same layout. grid (BB*AC), block 256.
__global__ __launch_bounds__(256)
void prepA_kernel(const float* __restrict__ A, u16* __restrict__ Ah)
{
    size_t base = (size_t)blockIdx.x * (NN * NN);
    int t = threadIdx.x;
    #pragma unroll
    for (int i = 0; i < 16; ++i) {
        int id = t + i * 256;          // 0..4095 float4s
        float4 v = *(const float4*)(A + base + (size_t)id * 4);
        u32 p0 = (u32)f2h(v.x) | ((u32)f2h(v.y) << 16);
        u32 p1 = (u32)f2h(v.z) | ((u32)f2h(v.w) << 16);
        *(uint2*)(Ah + base + (size_t)id * 4) = make_uint2(p0, p1);
    }
}

// ---------------------------------------------------------------------------
// prep: V fp32 [b][128][75] -> Vt fp16 [b][80][128] (transposed, rows 75..79 = 0)
__global__ __launch_bounds__(256)
void prepVt_kernel(const float* __restrict__ V, u16* __restrict__ Vt)
{
    int b = blockIdx.x, t = threadIdx.x;
    __shared__ float sV[NN * NF];
    for (int i = t; i < NN * NF; i += 256) sV[i] = V[(size_t)b * (NN * NF) + i];
    __syncthreads();
    for (int i = t; i < 80 * 128; i += 256) {
        int f = i >> 7, n = i & 127;
        float v = (f < NF) ? sV[n * NF + f] : 0.f;
        Vt[(size_t)b * (80 * 128) + i] = f2h(v);
    }
}

// ---------------------------------------------------------------------------
// Unified weight/fp prep. grid (256, 8), block 256. z sections:
// 0..2: gc Wt1/2/3; 3: fpW1t/W2t; 4: cross W transposes; 5/6: Wmlp br0/1;
// 7: fph rows.
__global__ __launch_bounds__(256)
void prepAllW_kernel(const float* __restrict__ gcW1, const float* __restrict__ gcW2,
                     const float* __restrict__ gcW3,
                     const float* __restrict__ fpW1, const float* __restrict__ fpW2,
                     const float* __restrict__ pfpW, const float* __restrict__ pvW,
                     const float* __restrict__ mfpW, const float* __restrict__ mvW,
                     const float* __restrict__ m1W,  const float* __restrict__ m2W,
                     const float* __restrict__ fp,
                     u16* __restrict__ Wt1, u16* __restrict__ Wt2, u16* __restrict__ Wt3,
                     u16* __restrict__ W1t, u16* __restrict__ W2t,
                     u16* __restrict__ pWt12, u16* __restrict__ mWt12,
                     u16* __restrict__ Wmlp, u16* __restrict__ fph)
{
    int o = blockIdx.x, z = blockIdx.y, t = threadIdx.x;
    if (z == 0) {
        int k = t;   // 0..255; layout k = c*80+f, pads zero
        int c = k / 80, f = k - c * 80;
        float v = (c < 3 && f < NF) ? gcW1[((size_t)c * NF + f) * HID + o] : 0.f;
        Wt1[(size_t)o * 256 + k] = f2h(v);
    } else if (z == 1 || z == 2) {
        const float* W = (z == 1) ? gcW2 : gcW3;
        u16* Wt = (z == 1) ? Wt2 : Wt3;
        for (int k = t; k < KB; k += 256) {
            int c = k >> 8, f = k & 255;
            Wt[(size_t)o * KB + k] = f2h(W[((size_t)c * HID + f) * HID + o]);
        }
    } else if (z == 3) {
        if (o < 128) {
            for (int k = t; k < FPDP; k += 256) {
                float v = (k < FPD) ? fpW1[(size_t)k * DIM + o] : 0.f;
                W1t[(size_t)o * FPDP + k] = f2h(v);
            }
            if (t < 128) W2t[(size_t)o * 128 + t] = f2h(fpW2[(size_t)t * DIM + o]);
        }
    } else if (z == 4) {
        if (o < 128 && t < 128) {
            pWt12[(size_t)0 * 16384 + o * 128 + t] = f2h(pfpW[(size_t)t * 128 + o]);
            pWt12[(size_t)1 * 16384 + o * 128 + t] = f2h(pvW [(size_t)t * 128 + o]);
            mWt12[(size_t)0 * 16384 + o * 128 + t] = f2h(mfpW[(size_t)t * 128 + o]);
            mWt12[(size_t)1 * 16384 + o * 128 + t] = f2h(mvW [(size_t)t * 128 + o]);
        }
    } else if (z == 5 || z == 6) {
        int br = z - 5;
        const float* W = br ? m2W : m1W;
        #pragma unroll
        for (int Lr = 0; Lr < 3; ++Lr)
            Wmlp[(((size_t)(br * 3 + Lr)) * 256 + o) * 256 + t] =
                f2h(W[(size_t)Lr * 256 * 256 + (size_t)t * 256 + o]);
    } else { // z == 7: fph row o
        for (int i = t; i < FPDP; i += 256) {
            float v = (i < FPD) ? fp[(size_t)o * FPD + i] : 0.f;
            fph[(size_t)o * FPDP + i] = f2h(v);
        }
    }
}

// ---------------------------------------------------------------------------
// fp chain fused (MFMA): layer1 tile -> LDS -> layer2. grid (2), block 256.
__global__ __launch_bounds__(256)
void fp12_mfma(const u16* __restrict__ fph, const u16* __restrict__ W1t,
               const float* __restrict__ b1, const u16* __restrict__ W2t,
               const float* __restrict__ b2, float* __restrict__ FP2,
               u16* __restrict__ FP2h)
{
    __shared__ u16 As[128 * 40];
    __shared__ u16 Bs[128 * 40];
    __shared__ u16 Xs[128 * 136];   // FP1 tile (stride 136: 16B-aligned rows)
    int mt = blockIdx.x;
    const u16* Ap = fph + (size_t)(mt * 128) * FPDP;

    int t = threadIdx.x;
    int l = t & 63, wid = t >> 6;
    int rb = (wid >> 1) * 64, cb = (wid & 1) * 64;
    int ln = l & 15, q = l >> 4;

    {
        f32x4 acc[4][4] = {};
        for (int kt = 0; kt < FPDP / 32; ++kt) {
            #pragma unroll
            for (int i = 0; i < 2; ++i) {
                int id = t + i * 256;
                int row = id >> 2, qh = id & 3;
                *(uint4*)&As[row * 40 + qh * 8] =
                    *(const uint4*)(Ap + (size_t)row * FPDP + kt * 32 + qh * 8);
                *(uint4*)&Bs[row * 40 + qh * 8] =
                    *(const uint4*)(W1t + (size_t)row * FPDP + kt * 32 + qh * 8);
            }
            __syncthreads();
            f16x8 af[4], bfr[4];
            #pragma unroll
            for (int fr = 0; fr < 4; ++fr)
                af[fr] = *(const f16x8*)&As[(rb + fr * 16 + ln) * 40 + q * 8];
            #pragma unroll
            for (int fc = 0; fc < 4; ++fc)
                bfr[fc] = *(const f16x8*)&Bs[(cb + fc * 16 + ln) * 40 + q * 8];
            #pragma unroll
            for (int fr = 0; fr < 4; ++fr)
                #pragma unroll
                for (int fc = 0; fc < 4; ++fc)
                    acc[fr][fc] = __builtin_amdgcn_mfma_f32_16x16x32_f16(
                        af[fr], bfr[fc], acc[fr][fc], 0, 0, 0);
            __syncthreads();
        }
        #pragma unroll
        for (int fr = 0; fr < 4; ++fr)
            #pragma unroll
            for (int fc = 0; fc < 4; ++fc) {
                int d = cb + fc * 16 + ln;
                float bv = b1[d];
                #pragma unroll
                for (int r = 0; r < 4; ++r) {
                    int m = rb + fr * 16 + q * 4 + r;
                    Xs[m * 136 + d] = f2h(fmaxf(acc[fr][fc][r] + bv, 0.f));
                }
            }
    }
    // layer 2: A from Xs
    f32x4 acc[4][4] = {};
    for (int kt = 0; kt < 4; ++kt) {
        __syncthreads();   // Xs ready (1st) / Bs consumed (rest)
        #pragma unroll
        for (int i = 0; i < 2; ++i) {
            int id = t + i * 256;
            int row = id >> 2, qh = id & 3;
            *(uint4*)&Bs[row * 40 + qh * 8] =
                *(const uint4*)(W2t + (size_t)row * 128 + kt * 32 + qh * 8);
        }
        __syncthreads();
        f16x8 af[4], bfr[4];
        #pragma unroll
        for (int fr = 0; fr < 4; ++fr)
            af[fr] = *(const f16x8*)&Xs[(rb + fr * 16 + ln) * 136 + kt * 32 + q * 8];
        #pragma unroll
        for (int fc = 0; fc < 4; ++fc)
            bfr[fc] = *(const f16x8*)&Bs[(cb + fc * 16 + ln) * 40 + q * 8];
        #pragma unroll
        for (int fr = 0; fr < 4; ++fr)
            #pragma unroll
            for (int fc = 0; fc < 4; ++fc)
                acc[fr][fc] = __builtin_amdgcn_mfma_f32_16x16x32_f16(
                    af[fr], bfr[fc], acc[fr][fc], 0, 0, 0);
    }
    #pragma unroll
    for (int fr = 0; fr < 4; ++fr)
        #pragma unroll
        for (int fc = 0; fc < 4; ++fc) {
            int d = cb + fc * 16 + ln;
            float bv = b2[d];
            #pragma unroll
            for (int r = 0; r < 4; ++r) {
                int m = rb + fr * 16 + q * 4 + r;
                float val = fmaxf(acc[fr][fc][r] + bv, 0.f);
                FP2 [(size_t)(mt * 128 + m) * 128 + d] = val;
                FP2h[(size_t)(mt * 128 + m) * 128 + d] = f2h(val);
            }
        }
}

// ---------------------------------------------------------------------------
// HS12 tables (MFMA): HS12[r][br*128+d] = fp16(relu(emb[r]@pW_br + b_br[d]))
__global__ __launch_bounds__(256)
void hs12_mfma(const float* __restrict__ emb, const u16* __restrict__ pWt12,
               const float* __restrict__ ba, const float* __restrict__ bb_,
               u16* __restrict__ HS12)
{
    __shared__ u16 As[128 * 40];
    __shared__ u16 Bs[128 * 40];
    int ft = blockIdx.x, br = blockIdx.y;
    const u16* Bp = pWt12 + (size_t)br * 128 * 128;
    const float* bias = br ? bb_ : ba;
    int r0 = ft * 128;

    int t = threadIdx.x;
    int l = t & 63, wid = t >> 6;
    int rb = (wid >> 1) * 64, cb = (wid & 1) * 64;
    int ln = l & 15, q = l >> 4;

    f32x4 acc[4][4] = {};

    for (int kt = 0; kt < 4; ++kt) {
        #pragma unroll
        for (int i = 0; i < 4; ++i) {
            int id = t + i * 256;
            int row = id >> 3, qf = id & 7;
            int r = r0 + row;
            float4 v = make_float4(0.f, 0.f, 0.f, 0.f);
            if (r < NWORD) v = *(const float4*)(emb + (size_t)r * 128 + kt * 32 + qf * 4);
            u32 p0 = (u32)f2h(v.x) | ((u32)f2h(v.y) << 16);
            u32 p1 = (u32)f2h(v.z) | ((u32)f2h(v.w) << 16);
            u32* dst = (u32*)&As[row * 40 + qf * 4];
            dst[0] = p0; dst[1] = p1;
        }
        #pragma unroll
        for (int i = 0; i < 2; ++i) {
            int id = t + i * 256;
            int row = id >> 2, qh = id & 3;
            *(uint4*)&Bs[row * 40 + qh * 8] =
                *(const uint4*)(Bp + (size_t)row * 128 + kt * 32 + qh * 8);
        }
        __syncthreads();
        f16x8 af[4], bfr[4];
        #pragma unroll
        for (int fr = 0; fr < 4; ++fr)
            af[fr] = *(const f16x8*)&As[(rb + fr * 16 + ln) * 40 + q * 8];
        #pragma unroll
        for (int fc = 0; fc < 4; ++fc)
            bfr[fc] = *(const f16x8*)&Bs[(cb + fc * 16 + ln) * 40 + q * 8];
        #pragma unroll
        for (int fr = 0; fr < 4; ++fr)
            #pragma unroll
            for (int fc = 0; fc < 4; ++fc)
                acc[fr][fc] = __builtin_amdgcn_mfma_f32_16x16x32_f16(
                    af[fr], bfr[fc], acc[fr][fc], 0, 0, 0);
        __syncthreads();
    }
    #pragma unroll
    for (int fr = 0; fr < 4; ++fr)
        #pragma unroll
        for (int fc = 0; fc < 4; ++fc) {
            int d = cb + fc * 16 + ln;
            float bv = bias[d];
            #pragma unroll
            for (int r = 0; r < 4; ++r) {
                int m = rb + fr * 16 + q * 4 + r;
                int rr = r0 + m;
                if (rr < NWORD)
                    HS12[(size_t)rr * 256 + br * 128 + d] = f2h(fmaxf(acc[fr][fc][r] + bv, 0.f));
            }
        }
}

// ---------------------------------------------------------------------------
// gA layer 1 (MFMA): AV[bl][n][c*80 + f] = (1/16)*sum_m Ah[b][c][n][m]*Vt[b][f][m]
__global__ __launch_bounds__(256)
void gA_mfma(const u16* __restrict__ Agr, const u16* __restrict__ Htr,
             u16* __restrict__ AV, int b0, int htStride, int fpMul, int Fvalid)
{
    __shared__ u16 As[128 * 40];
    __shared__ u16 Bs[128 * 40];
    int ft = blockIdx.x, c = blockIdx.y, bl = blockIdx.z;
    int b = b0 + bl;
    const u16* Ap = Agr + ((size_t)b * AC + c) * (NN * NN);
    const u16* Bp = Htr + (size_t)b * htStride + ft * (128 * 128);
    u16* Cp = AV + (size_t)bl * (NN * KB) + c * fpMul + ft * 128;

    int t = threadIdx.x;
    int l = t & 63, wid = t >> 6;
    int rb = (wid >> 1) * 64, cb = (wid & 1) * 64;
    int ln = l & 15, q = l >> 4;

    f32x4 acc[4][4] = {};

    for (int kt = 0; kt < 4; ++kt) {
        #pragma unroll
        for (int i = 0; i < 2; ++i) {
            int id = t + i * 256;
            int row = id >> 2, qh = id & 3;
            *(uint4*)&As[row * 40 + qh * 8] =
                *(const uint4*)(Ap + (size_t)row * NN + kt * 32 + qh * 8);
        }
        #pragma unroll
        for (int i = 0; i < 2; ++i) {
            int id = t + i * 256;
            int row = id >> 2, qh = id & 3;
            uint4 v = make_uint4(0, 0, 0, 0);
            if (row < Fvalid) v = *(const uint4*)(Bp + (size_t)row * 128 + kt * 32 + qh * 8);
            *(uint4*)&Bs[row * 40 + qh * 8] = v;
        }
        __syncthreads();
        f16x8 af[4], bfr[4];
        #pragma unroll
        for (int fr = 0; fr < 4; ++fr)
            af[fr] = *(const f16x8*)&As[(rb + fr * 16 + ln) * 40 + q * 8];
        #pragma unroll
        for (int fc = 0; fc < 4; ++fc)
            bfr[fc] = *(const f16x8*)&Bs[(cb + fc * 16 + ln) * 40 + q * 8];
        #pragma unroll
        for (int fr = 0; fr < 4; ++fr)
            #pragma unroll
            for (int fc = 0; fc < 4; ++fc)
                acc[fr][fc] = __builtin_amdgcn_mfma_f32_16x16x32_f16(
                    af[fr], bfr[fc], acc[fr][fc], 0, 0, 0);
        __syncthreads();
    }
    #pragma unroll
    for (int fr = 0; fr < 4; ++fr) {
        #pragma unroll
        for (int fc = 0; fc < 4; ++fc) {
            int fcol = cb + fc * 16 + ln;
            if (fcol < Fvalid) {
                #pragma unroll
                for (int r = 0; r < 4; ++r) {
                    int n = rb + fr * 16 + q * 4 + r;
                    Cp[(size_t)n * KB + fcol] = f2h_sat(acc[fr][fc][r] * SC);
                }
            }
        }
    }
}

// ---------------------------------------------------------------------------
// gA2 (layers 2/3): full A-tile staged once in LDS; both f-tiles per block.
__global__ __launch_bounds__(256)
void gA2_mfma(const u16* __restrict__ Agr, const u16* __restrict__ Htr,
              u16* __restrict__ AV, int b0)
{
    __shared__ u16 As[4][128 * 40];   // 40 KB: all 4 k-subtiles of A
    __shared__ u16 Bs[128 * 40];      // 10 KB
    int c = blockIdx.x, bl = blockIdx.y;
    int b = b0 + bl;
    const u16* Ap = Agr + ((size_t)b * AC + c) * (NN * NN);
    u16* Cp0 = AV + (size_t)bl * (NN * KB) + c * 256;

    int t = threadIdx.x;
    int l = t & 63, wid = t >> 6;
    int rb = (wid >> 1) * 64, cb = (wid & 1) * 64;
    int ln = l & 15, q = l >> 4;

    #pragma unroll
    for (int i = 0; i < 8; ++i) {
        int id = t + i * 256;
        int row = id >> 4, kq = id & 15;
        int kt = kq >> 2, qh = kq & 3;
        *(uint4*)&As[kt][row * 40 + qh * 8] =
            *(const uint4*)(Ap + (size_t)row * NN + kt * 32 + qh * 8);
    }

    for (int ft = 0; ft < 2; ++ft) {
        const u16* Bp = Htr + (size_t)b * (HID * NN) + ft * (128 * 128);
        f32x4 acc[4][4] = {};
        for (int kt = 0; kt < 4; ++kt) {
            __syncthreads();
            #pragma unroll
            for (int i = 0; i < 2; ++i) {
                int id = t + i * 256;
                int row = id >> 2, qh = id & 3;
                *(uint4*)&Bs[row * 40 + qh * 8] =
                    *(const uint4*)(Bp + (size_t)row * 128 + kt * 32 + qh * 8);
            }
            __syncthreads();
            f16x8 af[4], bfr[4];
            #pragma unroll
            for (int fr = 0; fr < 4; ++fr)
                af[fr] = *(const f16x8*)&As[kt][(rb + fr * 16 + ln) * 40 + q * 8];
            #pragma unroll
            for (int fc = 0; fc < 4; ++fc)
                bfr[fc] = *(const f16x8*)&Bs[(cb + fc * 16 + ln) * 40 + q * 8];
            #pragma unroll
            for (int fr = 0; fr < 4; ++fr)
                #pragma unroll
                for (int fc = 0; fc < 4; ++fc)
                    acc[fr][fc] = __builtin_amdgcn_mfma_f32_16x16x32_f16(
                        af[fr], bfr[fc], acc[fr][fc], 0, 0, 0);
        }
        #pragma unroll
        for (int fr = 0; fr < 4; ++fr)
            #pragma unroll
            for (int fc = 0; fc < 4; ++fc) {
                int fcol = ft * 128 + cb + fc * 16 + ln;
                #pragma unroll
                for (int r = 0; r < 4; ++r) {
                    int n = rb + fr * 16 + q * 4 + r;
                    Cp0[(size_t)n * KB + fcol] = f2h_sat(acc[fr][fc][r] * SC);
                }
            }
    }
}

// ---------------------------------------------------------------------------
// gB (MFMA): val[n][o] = relu( 16 * sum_k AVs[bl][n][k] * Wt[o][k] + bias[o] )
// mode 0 (layers 1-2): DIRECT transposed store to Ht [b][256][128] — each lane
//   owns 4 consecutive n at fixed oc -> one packed uint2 (no LDS tile).
// mode 1 (layer 3): write fp16 scaled 1/16 to H3h [b][n][256].
__global__ __launch_bounds__(256)
void gB_mfma(const u16* __restrict__ AV, const u16* __restrict__ Wt,
             const float* __restrict__ bias, u16* __restrict__ Hout,
             int b0, int kTiles, int Ks, int mode)
{
    __shared__ u16 As[128 * 40];
    __shared__ u16 Bs[128 * 40];
    int ot = blockIdx.x, bl = blockIdx.y;
    int b = b0 + bl;
    const u16* Ap = AV + (size_t)bl * (NN * KB);
    const u16* Bp = Wt + (size_t)ot * 128 * Ks;

    int t = threadIdx.x;
    int l = t & 63, wid = t >> 6;
    int rb = (wid >> 1) * 64, cb = (wid & 1) * 64;
    int ln = l & 15, q = l >> 4;

    f32x4 acc[4][4] = {};

    for (int kt = 0; kt < kTiles; ++kt) {
        #pragma unroll
        for (int i = 0; i < 2; ++i) {
            int id = t + i * 256;
            int row = id >> 2, qh = id & 3;
            *(uint4*)&As[row * 40 + qh * 8] =
                *(const uint4*)(Ap + (size_t)row * KB + kt * 32 + qh * 8);
            *(uint4*)&Bs[row * 40 + qh * 8] =
                *(const uint4*)(Bp + (size_t)row * Ks + kt * 32 + qh * 8);
        }
        __syncthreads();
        f16x8 af[4], bfr[4];
        #pragma unroll
        for (int fr = 0; fr < 4; ++fr)
            af[fr] = *(const f16x8*)&As[(rb + fr * 16 + ln) * 40 + q * 8];
        #pragma unroll
        for (int fc = 0; fc < 4; ++fc)
            bfr[fc] = *(const f16x8*)&Bs[(cb + fc * 16 + ln) * 40 + q * 8];
        #pragma unroll
        for (int fr = 0; fr < 4; ++fr)
            #pragma unroll
            for (int fc = 0; fc < 4; ++fc)
                acc[fr][fc] = __builtin_amdgcn_mfma_f32_16x16x32_f16(
                    af[fr], bfr[fc], acc[fr][fc], 0, 0, 0);
        __syncthreads();
    }
    if (mode == 0) {
        #pragma unroll
        for (int fr = 0; fr < 4; ++fr)
            #pragma unroll
            for (int fc = 0; fc < 4; ++fc) {
                int oc = cb + fc * 16 + ln;
                float bv = bias[ot * 128 + oc];
                int n0 = rb + fr * 16 + q * 4;
                u16 v0 = f2h_sat(fmaxf(acc[fr][fc][0] * USC + bv, 0.f));
                u16 v1 = f2h_sat(fmaxf(acc[fr][fc][1] * USC + bv, 0.f));
                u16 v2 = f2h_sat(fmaxf(acc[fr][fc][2] * USC + bv, 0.f));
                u16 v3 = f2h_sat(fmaxf(acc[fr][fc][3] * USC + bv, 0.f));
                uint2 pk = make_uint2((u32)v0 | ((u32)v1 << 16),
                                      (u32)v2 | ((u32)v3 << 16));
                *(uint2*)(Hout + ((size_t)b * HID + ot * 128 + oc) * NN + n0) = pk;
            }
    } else {
        #pragma unroll
        for (int fr = 0; fr < 4; ++fr)
            #pragma unroll
            for (int fc = 0; fc < 4; ++fc) {
                int oc = cb + fc * 16 + ln;
                float bv = bias[ot * 128 + oc];
                #pragma unroll
                for (int r = 0; r < 4; ++r) {
                    int n = rb + fr * 16 + q * 4 + r;
                    float val = fmaxf(acc[fr][fc][r] * USC + bv, 0.f);
                    Hout[((size_t)b * NN + n) * HID + ot * 128 + oc] = f2h_sat(val * SC);
                }
            }
    }
}

// ---------------------------------------------------------------------------
// Masked multi-head attention pooling. H3h fp16 scaled 1/16; single-pass.
__global__ __launch_bounds__(256)
void pool_kernel(const u16* __restrict__ H3h,
                 const float* __restrict__ attW,
                 const int* __restrict__ msz,
                 float* __restrict__ pooled)
{
    int b = blockIdx.x, t = threadIdx.x;
    __shared__ u16  sTh[128][264];
    __shared__ float sW[HID * NHEAD];
    __shared__ float sS[NN * NHEAD];
    __shared__ float sP[16][NHEAD][2];
    for (int i = t; i < HID * NHEAD; i += 256) sW[i] = attW[i];
    const u16* Hb = H3h + (size_t)b * NN * HID;
    for (int i = t; i < 128 * 32; i += 256) {
        int row = i >> 5, fq = (i & 31) * 8;
        *(uint4*)&sTh[row][fq] = *(const uint4*)(Hb + (size_t)row * HID + fq);
    }
    __syncthreads();
    for (int n0 = 0; n0 < NN; n0 += 16) {
        int nl = t >> 4, h = (t >> 1) & 7, fh = t & 1;
        float s = 0.f;
        for (int f = fh * 128; f < fh * 128 + 128; ++f)
            s += h2f(sTh[n0 + nl][f]) * sW[f * NHEAD + h];
        sP[nl][h][fh] = s;
        __syncthreads();
        if (t < 128) {
            int n2 = t >> 3, h2 = t & 7;
            sS[(n0 + n2) * NHEAD + h2] = USC * (sP[n2][h2][0] + sP[n2][h2][1]);
        }
        __syncthreads();
    }
    int ms = msz[b];
    int h = t >> 5, ln = t & 31;
    float mx = -1e9f;
    for (int n = ln; n < NN; n += 32) {
        float s = (n < ms) ? sS[n * NHEAD + h] : -1e9f;
        mx = fmaxf(mx, s);
    }
    #pragma unroll
    for (int off = 16; off; off >>= 1) mx = fmaxf(mx, __shfl_xor(mx, off, 32));
    float sum = 0.f;
    for (int n = ln; n < NN; n += 32) {
        float s = (n < ms) ? sS[n * NHEAD + h] : -1e9f;
        sum += expf(s - mx);
    }
    #pragma unroll
    for (int off = 16; off; off >>= 1) sum += __shfl_xor(sum, off, 32);
    float inv = 1.f / sum;
    for (int n = ln; n < NN; n += 32) {
        float s = (n < ms) ? sS[n * NHEAD + h] : -1e9f;
        sS[n * NHEAD + h] = expf(s - mx) * inv;
    }
    __syncthreads();
    float accp[NHEAD] = {};
    for (int n = 0; n < NN; ++n) {
        float hv = h2f(sTh[n][t]);
        #pragma unroll
        for (int hh = 0; hh < NHEAD; ++hh) accp[hh] += sS[n * NHEAD + hh] * hv;
    }
    #pragma unroll
    for (int hh = 0; hh < NHEAD; ++hh)
        pooled[(size_t)b * (HID * NHEAD) + hh * HID + t] = USC * accp[hh];
}

// ---------------------------------------------------------------------------
// Readout, k-split
__global__ __launch_bounds__(128)
void readout_part(const float* __restrict__ pooled,
                  const float* __restrict__ roW,
                  float* __restrict__ Rp)
{
    int b = blockIdx.x, s = blockIdx.y, t = threadIdx.x;
    __shared__ float sx[256];
    const float* sp = pooled + (size_t)b * (HID * NHEAD) + s * 256;
    sx[t] = sp[t];
    sx[t + 128] = sp[t + 128];
    __syncthreads();
    float acc = 0.f;
    const float* W = roW + (size_t)(s * 256) * DIM + t;
    for (int k = 0; k < 256; ++k) acc += sx[k] * W[(size_t)k * DIM];
    Rp[((size_t)s * BB + b) * DIM + t] = acc;
}

__global__ __launch_bounds__(128)
void readout_merge(const float* __restrict__ Rp,
                   const float* __restrict__ rob,
                   float* __restrict__ Vr, u16* __restrict__ Vrh)
{
    int b = blockIdx.x, t = threadIdx.x;
    float a = rob[t];
    #pragma unroll
    for (int s = 0; s < 8; ++s) a += Rp[((size_t)s * BB + b) * DIM + t];
    float v = fmaxf(a, 0.f);
    Vr [(size_t)b * DIM + t] = v;
    Vrh[(size_t)b * DIM + t] = f2h_sat(v * SC);   // scaled 1/16
}

// ---------------------------------------------------------------------------
// atth (MFMA): h_br = relu(X_br @ W_br + b_br) -> fp16 out. grid (2 mt, 2 br).
__global__ __launch_bounds__(256)
void atth_mfma(const u16* __restrict__ FP2h, const u16* __restrict__ VRh,
               const u16* __restrict__ mWt12,
               const float* __restrict__ mfpb, const float* __restrict__ mvb,
               u16* __restrict__ h1h, u16* __restrict__ h2h)
{
    __shared__ u16 As[128 * 40];
    __shared__ u16 Bs[128 * 40];
    int mt = blockIdx.x, br = blockIdx.y;
    const u16* Ap = (br ? VRh : FP2h) + (size_t)(mt * 128) * 128;
    const u16* Bp = mWt12 + (size_t)br * 128 * 128;
    const float* bias = br ? mvb : mfpb;
    float unsc = br ? USC : 1.f;
    u16* out = br ? h2h : h1h;

    int t = threadIdx.x;
    int l = t & 63, wid = t >> 6;
    int rb = (wid >> 1) * 64, cb = (wid & 1) * 64;
    int ln = l & 15, q = l >> 4;

    f32x4 acc[4][4] = {};

    for (int kt = 0; kt < 4; ++kt) {
        #pragma unroll
        for (int i = 0; i < 2; ++i) {
            int id = t + i * 256;
            int row = id >> 2, qh = id & 3;
            *(uint4*)&As[row * 40 + qh * 8] =
                *(const uint4*)(Ap + (size_t)row * 128 + kt * 32 + qh * 8);
            *(uint4*)&Bs[row * 40 + qh * 8] =
                *(const uint4*)(Bp + (size_t)row * 128 + kt * 32 + qh * 8);
        }
        __syncthreads();
        f16x8 af[4], bfr[4];
        #pragma unroll
        for (int fr = 0; fr < 4; ++fr)
            af[fr] = *(const f16x8*)&As[(rb + fr * 16 + ln) * 40 + q * 8];
        #pragma unroll
        for (int fc = 0; fc < 4; ++fc)
            bfr[fc] = *(const f16x8*)&Bs[(cb + fc * 16 + ln) * 40 + q * 8];
        #pragma unroll
        for (int fr = 0; fr < 4; ++fr)
            #pragma unroll
            for (int fc = 0; fc < 4; ++fc)
                acc[fr][fc] = __builtin_amdgcn_mfma_f32_16x16x32_f16(
                    af[fr], bfr[fc], acc[fr][fc], 0, 0, 0);
        __syncthreads();
    }
    #pragma unroll
    for (int fr = 0; fr < 4; ++fr)
        #pragma unroll
        for (int fc = 0; fc < 4; ++fc) {
            int d = cb + fc * 16 + ln;
            float bv = bias[d];
            #pragma unroll
            for (int r = 0; r < 4; ++r) {
                int m = rb + fr * 16 + q * 4 + r;
                out[(size_t)(mt * 128 + m) * 128 + d] =
                    f2h_sat(fmaxf(acc[fr][fc][r] * unsc + bv, 0.f));
            }
        }
}

// ---------------------------------------------------------------------------
// Cross-attn partial scan: fdot2 dot products, packed-fp16 max, fast tanh.
__global__ __launch_bounds__(256)
void cross_part_kernel(const int* __restrict__ seq,
                       const u16* __restrict__ HS12,
                       const u16* __restrict__ h1h, const u16* __restrict__ h2h,
                       float* __restrict__ Pc)   // [8][B][2][128]
{
    int b = blockIdx.x, s = blockIdx.y, t = threadIdx.x;
    int g = t >> 4, gl = t & 15;
    int d0 = gl * 8;
    f16x8 h1 = *(const f16x8*)(h1h + (size_t)b * DIM + d0);
    f16x8 h2 = *(const f16x8*)(h2h + (size_t)b * DIM + d0);
    const h2v* h1p = (const h2v*)&h1;
    const h2v* h2p = (const h2v*)&h2;
    h2v m1[4], m2[4];
    _Float16 NEGBIG = (_Float16)(-65504.f);
    #pragma unroll
    for (int k = 0; k < 4; ++k) { m1[k] = (h2v){NEGBIG, NEGBIG}; m2[k] = (h2v){NEGBIG, NEGBIG}; }
    const int* sq = seq + (size_t)b * LL + s * 256;
    for (int it = 0; it < 16; ++it) {
        int tok = sq[g + 16 * it];
        const u16* r12 = HS12 + (size_t)tok * 256 + d0;
        f16x8 va = *(const f16x8*)(r12);
        f16x8 vb = *(const f16x8*)(r12 + 128);
        const h2v* vap = (const h2v*)&va;
        const h2v* vbp = (const h2v*)&vb;
        float p1 = 0.f, p2 = 0.f;
        #pragma unroll
        for (int k = 0; k < 4; ++k) {
            p1 = __builtin_amdgcn_fdot2(vap[k], h1p[k], p1, false);
            p2 = __builtin_amdgcn_fdot2(vbp[k], h2p[k], p2, false);
        }
        #pragma unroll
        for (int off = 8; off; off >>= 1) {
            p1 += __shfl_xor(p1, off);
            p2 += __shfl_xor(p2, off);
        }
        float w1 = 1.f - 2.f / (__expf(2.f * p1) + 1.f);
        float w2 = 1.f - 2.f / (__expf(2.f * p2) + 1.f);
        _Float16 w1s = (_Float16)w1, w2s = (_Float16)w2;
        h2v w1p = (h2v){w1s, w1s}, w2p = (h2v){w2s, w2s};
        #pragma unroll
        for (int k = 0; k < 4; ++k) {
            h2v pr1 = w1p * vap[k];
            h2v pr2 = w2p * vbp[k];
            m1[k] = (h2v){ m1[k][0] > pr1[0] ? m1[k][0] : pr1[0],
                           m1[k][1] > pr1[1] ? m1[k][1] : pr1[1] };
            m2[k] = (h2v){ m2[k][0] > pr2[0] ? m2[k][0] : pr2[0],
                           m2[k][1] > pr2[1] ? m2[k][1] : pr2[1] };
        }
    }
    __shared__ float red[16][2][DIM];
    #pragma unroll
    for (int k = 0; k < 4; ++k) {
        red[g][0][d0 + 2 * k]     = (float)m1[k][0];
        red[g][0][d0 + 2 * k + 1] = (float)m1[k][1];
        red[g][1][d0 + 2 * k]     = (float)m2[k][0];
        red[g][1][d0 + 2 * k + 1] = (float)m2[k][1];
    }
    __syncthreads();
    int tb = t >> 7, d = t & 127;
    float mx = red[0][tb][d];
    #pragma unroll
    for (int gg = 1; gg < 16; ++gg) mx = fmaxf(mx, red[gg][tb][d]);
    Pc[(((size_t)s * BB + b) * 2 + tb) * DIM + d] = mx;
}

// ---------------------------------------------------------------------------
// Fused MLP: input build (incl. cross merge) + 3 MFMA layers, LDS ping-pong.
// grid (2 mt, 2 br), block 256. Output Yf [br][BB][256] fp16 scaled 1/16.
__global__ __launch_bounds__(256)
void mlp3_mfma(const float* __restrict__ FP2, const float* __restrict__ VR,
               const float* __restrict__ Pc, const u16* __restrict__ Wmlp,
               const float* __restrict__ m1b, const float* __restrict__ m2b,
               u16* __restrict__ Yf)
{
    __shared__ u16 XY[2][128 * 264];   // 135 KB ping-pong (stride 264: 16B rows)
    __shared__ u16 Bs[128 * 40];
    int mt = blockIdx.x, br = blockIdx.y;
    int t = threadIdx.x;

    // build input rows (batch b = mt*128 + row), scaled 1/16
    for (int i = t; i < 128 * 256; i += 256) {
        int row = i >> 8, col = i & 255;
        int b = mt * 128 + row;
        float v;
        if (col < 128) {
            v = (br ? VR : FP2)[(size_t)b * 128 + col];
        } else {
            int d = col - 128;
            float m = -INFINITY;
            #pragma unroll
            for (int s = 0; s < 8; ++s)
                m = fmaxf(m, Pc[(((size_t)s * BB + b) * 2 + br) * DIM + d]);
            v = m;
        }
        XY[0][row * 264 + col] = f2h_sat(v * SC);
    }

    int l = t & 63, wid = t >> 6;
    int rb = (wid >> 1) * 64, cb = (wid & 1) * 64;
    int ln = l & 15, q = l >> 4;

    int cur = 0;
    for (int Lr = 0; Lr < 3; ++Lr) {
        const float* bias = (br ? m2b : m1b) + (size_t)Lr * 256;
        for (int ot = 0; ot < 2; ++ot) {
            const u16* Bp = Wmlp + (((size_t)(br * 3 + Lr)) * 256 + ot * 128) * 256;
            f32x4 acc[4][4] = {};
            for (int kt = 0; kt < 8; ++kt) {
                __syncthreads();   // input/prev-layer ready + Bs consumed
                #pragma unroll
                for (int i = 0; i < 2; ++i) {
                    int id = t + i * 256;
                    int row = id >> 2, qh = id & 3;
                    *(uint4*)&Bs[row * 40 + qh * 8] =
                        *(const uint4*)(Bp + (size_t)row * 256 + kt * 32 + qh * 8);
                }
                __syncthreads();
                f16x8 af[4], bfr[4];
                #pragma unroll
                for (int fr = 0; fr < 4; ++fr)
                    af[fr] = *(const f16x8*)&XY[cur][(rb + fr * 16 + ln) * 264 + kt * 32 + q * 8];
                #pragma unroll
                for (int fc = 0; fc < 4; ++fc)
                    bfr[fc] = *(const f16x8*)&Bs[(cb + fc * 16 + ln) * 40 + q * 8];
                #pragma unroll
                for (int fr = 0; fr < 4; ++fr)
                    #pragma unroll
                    for (int fc = 0; fc < 4; ++fc)
                        acc[fr][fc] = __builtin_amdgcn_mfma_f32_16x16x32_f16(
                            af[fr], bfr[fc], acc[fr][fc], 0, 0, 0);
            }
            // write to the other buffer; y = relu(acc + b/16) (scaled)
            #pragma unroll
            for (int fr = 0; fr < 4; ++fr)
                #pragma unroll
                for (int fc = 0; fc < 4; ++fc) {
                    int oc = cb + fc * 16 + ln;
                    float bv = bias[ot * 128 + oc] * SC;
                    #pragma unroll
                    for (int r = 0; r < 4; ++r) {
                        int m = rb + fr * 16 + q * 4 + r;
                        XY[cur ^ 1][m * 264 + ot * 128 + oc] =
                            f2h_sat(fmaxf(acc[fr][fc][r] + bv, 0.f));
                    }
                }
        }
        cur ^= 1;
    }
    __syncthreads();
    // final result in XY[cur]; write to global
    for (int i = t; i < 128 * 32; i += 256) {
        int row = i >> 5, c8 = (i & 31) * 8;
        *(uint4*)(Yf + ((size_t)br * BB + mt * 128 + row) * 256 + c8) =
            *(const uint4*)&XY[cur][row * 264 + c8];
    }
}

// head + outputs. grid (BB), block 256.
__global__ __launch_bounds__(256)
void mlp_out_kernel(const u16* __restrict__ Y,
                    const float* __restrict__ o1W, const float* __restrict__ o1b,
                    const float* __restrict__ o2W, const float* __restrict__ o2b,
                    const int* __restrict__ label,
                    float* __restrict__ dout)
{
    int b = blockIdx.x, t = threadIdx.x;
    __shared__ float pl[2][128];
    const u16* y1 = Y + (size_t)b * 256;
    const u16* y2 = Y + ((size_t)BB + b) * 256;
    int j = t & 1, k2 = t >> 1;
    float p = USC * (h2f(y1[k2])       * o1W[k2 * 2 + j]
                   + h2f(y1[k2 + 128]) * o1W[(k2 + 128) * 2 + j]
                   + h2f(y2[k2])       * o2W[k2 * 2 + j]
                   + h2f(y2[k2 + 128]) * o2W[(k2 + 128) * 2 + j]);
    pl[j][k2] = p;
    __syncthreads();
    for (int s = 64; s > 0; s >>= 1) {
        if (k2 < s) pl[j][k2] += pl[j][k2 + s];
        __syncthreads();
    }
    if (t == 0) {
        float l0 = pl[0][0] + o1b[0] + o2b[0];
        float l1 = pl[1][0] + o1b[1] + o2b[1];
        dout[(size_t)b * 2 + 0] = l0;
        dout[(size_t)b * 2 + 1] = l1;
        dout[2 * BB + b] = (float)label[b];
        dout[3 * BB + b] = (float)((l1 > l0) ? 1 : 0);
        float mx = fmaxf(l0, l1);
        float e0 = expf(l0 - mx), e1 = expf(l1 - mx);
        dout[4 * BB + b] = e1 / (e0 + e1);
    }
}

// ---------------------------------------------------------------------------
extern "C" void kernel_launch(void* const* d_in, const int* in_sizes, int n_in,
                              void* d_out, int out_size, void* d_ws, size_t ws_size,
                              hipStream_t stream)
{
    const float* V    = (const float*)d_in[0];
    const float* A    = (const float*)d_in[1];
    const float* fp   = (const float*)d_in[2];
    const int*   msz  = (const int*)  d_in[3];
    const int*   seq  = (const int*)  d_in[4];
    const int*   lab  = (const int*)  d_in[5];
    const float* gcW1 = (const float*)d_in[6];  const float* gcb1 = (const float*)d_in[7];
    const float* gcW2 = (const float*)d_in[8];  const float* gcb2 = (const float*)d_in[9];
    const float* gcW3 = (const float*)d_in[10]; const float* gcb3 = (const float*)d_in[11];
    const float* fpW1 = (const float*)d_in[12]; const float* fpb1 = (const float*)d_in[13];
    const float* fpW2 = (const float*)d_in[14]; const float* fpb2 = (const float*)d_in[15];
    const float* attW = (const float*)d_in[16];
    const float* roW  = (const float*)d_in[17]; const float* rob  = (const float*)d_in[18];
    const float* emb  = (const float*)d_in[19];
    const float* mfpW = (const float*)d_in[20]; const float* mfpb = (const float*)d_in[21];
    const float* pfpW = (const float*)d_in[22]; const float* pfpb = (const float*)d_in[23];
    const float* mvW  = (const float*)d_in[24]; const float* mvb  = (const float*)d_in[25];
    const float* pvW  = (const float*)d_in[26]; const float* pvb  = (const float*)d_in[27];
    const float* m1W  = (const float*)d_in[28]; const float* m1b  = (const float*)d_in[29];
    const float* m2W  = (const float*)d_in[30]; const float* m2b  = (const float*)d_in[31];
    const float* o1W  = (const float*)d_in[32]; const float* o1b  = (const float*)d_in[33];
    const float* o2W  = (const float*)d_in[34]; const float* o2b  = (const float*)d_in[35];
    float* dout = (float*)d_out;

    // workspace layout
    char* ws = (char*)d_ws;
    size_t off = 0;
    auto alloc = [&](size_t bytes) -> char* {
        char* p = ws + off;
        off += (bytes + 255) & ~(size_t)255;
        return p;
    };
    u16*   Ah    = (u16*)  alloc((size_t)BB * AC * NN * NN * 2);   // 25.2 MB
    u16*   Vt    = (u16*)  alloc((size_t)BB * 80 * 128 * 2);       // 5.24 MB
    u16*   Wt1   = (u16*)  alloc((size_t)256 * 256 * 2);
    u16*   Wt2   = (u16*)  alloc((size_t)256 * KB * 2);
    u16*   Wt3   = (u16*)  alloc((size_t)256 * KB * 2);
    u16*   Ht    = (u16*)  alloc((size_t)BB * HID * NN * 2);       // 16.8 MB
    u16*   H3h   = (u16*)  alloc((size_t)BB * NN * HID * 2);       // 16.8 MB (fp16, 1/16)
    u16*   fph   = (u16*)  alloc((size_t)BB * FPDP * 2);
    u16*   W1t   = (u16*)  alloc((size_t)DIM * FPDP * 2);
    u16*   W2t   = (u16*)  alloc((size_t)DIM * DIM * 2);
    float* FP2   = (float*)alloc((size_t)BB * DIM * 4);
    u16*   FP2h  = (u16*)  alloc((size_t)BB * DIM * 2);
    u16*   pWt12 = (u16*)  alloc((size_t)2 * 128 * 128 * 2);
    u16*   mWt12 = (u16*)  alloc((size_t)2 * 128 * 128 * 2);
    u16*   HS12  = (u16*)  alloc((size_t)NWP * 256 * 2);           // 4.45 MB
    float* PO    = (float*)alloc((size_t)BB * HID * NHEAD * 4);
    float* VR    = (float*)alloc((size_t)BB * DIM * 4);
    u16*   VRh   = (u16*)  alloc((size_t)BB * DIM * 2);
    u16*   h1h   = (u16*)  alloc((size_t)BB * DIM * 2);
    u16*   h2h   = (u16*)  alloc((size_t)BB * DIM * 2);
    float* Pc    = (float*)alloc((size_t)8 * BB * 2 * DIM * 4);
    float* Rp    = (float*)alloc((size_t)8 * BB * DIM * 4);
    u16*   Wmlp  = (u16*)  alloc((size_t)2 * 3 * 256 * 256 * 2);   // 786 KB
    u16*   Yf    = (u16*)  alloc((size_t)2 * BB * 256 * 2);        // 256 KB
    size_t fixedBytes = off;

    // AV tier (fp16, per-b 128*768*2 = 196608 B)
    int CB = 8;
    size_t perB = (size_t)NN * KB * 2;
    {
        const int tiers[] = {256, 128, 64, 32, 16, 8, 4, 2, 1};
        for (int i = 0; i < 9; ++i)
            if (fixedBytes + (size_t)tiers[i] * perB <= ws_size) { CB = tiers[i]; break; }
    }
    u16* AV = (u16*)(ws + fixedBytes);

    // prep + independent front-end
    prepA_kernel<<<BB * AC, 256, 0, stream>>>(A, Ah);
    prepVt_kernel<<<BB, 256, 0, stream>>>(V, Vt);
    prepAllW_kernel<<<dim3(256, 8), 256, 0, stream>>>(
        gcW1, gcW2, gcW3, fpW1, fpW2, pfpW, pvW, mfpW, mvW, m1W, m2W, fp,
        Wt1, Wt2, Wt3, W1t, W2t, pWt12, mWt12, Wmlp, fph);
    fp12_mfma<<<2, 256, 0, stream>>>(fph, W1t, fpb1, W2t, fpb2, FP2, FP2h);
    hs12_mfma<<<dim3(NWP / 128, 2), 256, 0, stream>>>(emb, pWt12, pfpb, pvb, HS12);

    // GConv layer 1 (F=75 padded to 80; gB writes Ht directly, transposed)
    for (int b0 = 0; b0 < BB; b0 += CB) {
        gA_mfma<<<dim3(1, AC, CB), 256, 0, stream>>>(Ah, Vt, AV, b0, 80 * 128, 80, 80);
        gB_mfma<<<dim3(2, CB), 256, 0, stream>>>(AV, Wt1, gcb1, Ht, b0, 8, 256, 0);
    }
    // layer 2
    for (int b0 = 0; b0 < BB; b0 += CB) {
        gA2_mfma<<<dim3(AC, CB), 256, 0, stream>>>(Ah, Ht, AV, b0);
        gB_mfma<<<dim3(2, CB), 256, 0, stream>>>(AV, Wt2, gcb2, Ht, b0, 24, KB, 0);
    }
    // layer 3 -> H3h fp16 scaled 1/16
    for (int b0 = 0; b0 < BB; b0 += CB) {
        gA2_mfma<<<dim3(AC, CB), 256, 0, stream>>>(Ah, Ht, AV, b0);
        gB_mfma<<<dim3(2, CB), 256, 0, stream>>>(AV, Wt3, gcb3, H3h, b0, 24, KB, 1);
    }

    pool_kernel<<<BB, 256, 0, stream>>>(H3h, attW, msz, PO);
    readout_part<<<dim3(BB, 8), 128, 0, stream>>>(PO, roW, Rp);
    readout_merge<<<BB, 128, 0, stream>>>(Rp, rob, VR, VRh);
    atth_mfma<<<dim3(2, 2), 256, 0, stream>>>(FP2h, VRh, mWt12, mfpb, mvb, h1h, h2h);
    cross_part_kernel<<<dim3(BB, 8), 256, 0, stream>>>(seq, HS12, h1h, h2h, Pc);
    mlp3_mfma<<<dim3(2, 2), 256, 0, stream>>>(FP2, VR, Pc, Wmlp, m1b, m2b, Yf);
    mlp_out_kernel<<<BB, 256, 0, stream>>>(Yf, o1W, o1b, o2W, o2b, lab, dout);
}

// Round 12
// 472.788 us; speedup vs baseline: 1.1037x; 1.1037x over previous
//
#include <hip/hip_runtime.h>
#include <math.h>

// Problem constants
static constexpr int BB   = 256;   // batch
static constexpr int NN   = 128;   // nodes
static constexpr int LL   = 2048;  // protein length
static constexpr int NF   = 75;
static constexpr int AC   = 3;
static constexpr int HID  = 256;
static constexpr int DIM  = 128;
static constexpr int NHEAD= 8;
static constexpr int FPD  = 679;
static constexpr int FPDP = 704;   // FPD padded to multiple of 32
static constexpr int NWORD= 8600;
static constexpr int NWP  = 8704;  // NWORD padded to 68*128
static constexpr int KB   = 768;   // AV row stride (3*256)

typedef __attribute__((ext_vector_type(8))) _Float16 f16x8;
typedef __attribute__((ext_vector_type(2))) _Float16 h2v;
typedef __attribute__((ext_vector_type(4))) float f32x4;
typedef unsigned int u32;
typedef unsigned short u16;

__device__ __forceinline__ u16 f2h(float x) {
    _Float16 h = (_Float16)x;       // RNE
    return *(u16*)&h;
}
// saturating fp32->fp16 (avoid inf from rare tail values)
__device__ __forceinline__ u16 f2h_sat(float x) {
    x = fminf(fmaxf(x, -65000.f), 65000.f);
    _Float16 h = (_Float16)x;
    return *(u16*)&h;
}
__device__ __forceinline__ float h2f(u16 x) {
    return (float)(*(_Float16*)&x);
}

// fp16-carried intermediates with large range are stored scaled by 1/16.
static constexpr float SC   = 0.0625f;
static constexpr float USC  = 16.0f;

// ---------------------------------------------------------------------------
// prep: A fp32 -> fp16, same layout. grid (BB*AC), block 256.
__global__ __launch_bounds__(256)
void prepA_kernel(const float* __restrict__ A, u16* __restrict__ Ah)
{
    size_t base = (size_t)blockIdx.x * (NN * NN);
    int t = threadIdx.x;
    #pragma unroll
    for (int i = 0; i < 16; ++i) {
        int id = t + i * 256;          // 0..4095 float4s
        float4 v = *(const float4*)(A + base + (size_t)id * 4);
        u32 p0 = (u32)f2h(v.x) | ((u32)f2h(v.y) << 16);
        u32 p1 = (u32)f2h(v.z) | ((u32)f2h(v.w) << 16);
        *(uint2*)(Ah + base + (size_t)id * 4) = make_uint2(p0, p1);
    }
}

// ---------------------------------------------------------------------------
// prep: V fp32 [b][128][75] -> Vt fp16 [b][80][128] (transposed, rows 75..79 = 0)
__global__ __launch_bounds__(256)
void prepVt_kernel(const float* __restrict__ V, u16* __restrict__ Vt)
{
    int b = blockIdx.x, t = threadIdx.x;
    __shared__ float sV[NN * NF];
    for (int i = t; i < NN * NF; i += 256) sV[i] = V[(size_t)b * (NN * NF) + i];
    __syncthreads();
    for (int i = t; i < 80 * 128; i += 256) {
        int f = i >> 7, n = i & 127;
        float v = (f < NF) ? sV[n * NF + f] : 0.f;
        Vt[(size_t)b * (80 * 128) + i] = f2h(v);
    }
}

// ---------------------------------------------------------------------------
// Unified weight/fp prep. grid (256, 8), block 256.
__global__ __launch_bounds__(256)
void prepAllW_kernel(const float* __restrict__ gcW1, const float* __restrict__ gcW2,
                     const float* __restrict__ gcW3,
                     const float* __restrict__ fpW1, const float* __restrict__ fpW2,
                     const float* __restrict__ pfpW, const float* __restrict__ pvW,
                     const float* __restrict__ mfpW, const float* __restrict__ mvW,
                     const float* __restrict__ m1W,  const float* __restrict__ m2W,
                     const float* __restrict__ fp,
                     u16* __restrict__ Wt1, u16* __restrict__ Wt2, u16* __restrict__ Wt3,
                     u16* __restrict__ W1t, u16* __restrict__ W2t,
                     u16* __restrict__ pWt12, u16* __restrict__ mWt12,
                     u16* __restrict__ Wmlp, u16* __restrict__ fph)
{
    int o = blockIdx.x, z = blockIdx.y, t = threadIdx.x;
    if (z == 0) {
        int k = t;   // 0..255; layout k = c*80+f, pads zero
        int c = k / 80, f = k - c * 80;
        float v = (c < 3 && f < NF) ? gcW1[((size_t)c * NF + f) * HID + o] : 0.f;
        Wt1[(size_t)o * 256 + k] = f2h(v);
    } else if (z == 1 || z == 2) {
        const float* W = (z == 1) ? gcW2 : gcW3;
        u16* Wt = (z == 1) ? Wt2 : Wt3;
        for (int k = t; k < KB; k += 256) {
            int c = k >> 8, f = k & 255;
            Wt[(size_t)o * KB + k] = f2h(W[((size_t)c * HID + f) * HID + o]);
        }
    } else if (z == 3) {
        if (o < 128) {
            for (int k = t; k < FPDP; k += 256) {
                float v = (k < FPD) ? fpW1[(size_t)k * DIM + o] : 0.f;
                W1t[(size_t)o * FPDP + k] = f2h(v);
            }
            if (t < 128) W2t[(size_t)o * 128 + t] = f2h(fpW2[(size_t)t * DIM + o]);
        }
    } else if (z == 4) {
        if (o < 128 && t < 128) {
            pWt12[(size_t)0 * 16384 + o * 128 + t] = f2h(pfpW[(size_t)t * 128 + o]);
            pWt12[(size_t)1 * 16384 + o * 128 + t] = f2h(pvW [(size_t)t * 128 + o]);
            mWt12[(size_t)0 * 16384 + o * 128 + t] = f2h(mfpW[(size_t)t * 128 + o]);
            mWt12[(size_t)1 * 16384 + o * 128 + t] = f2h(mvW [(size_t)t * 128 + o]);
        }
    } else if (z == 5 || z == 6) {
        int br = z - 5;
        const float* W = br ? m2W : m1W;
        #pragma unroll
        for (int Lr = 0; Lr < 3; ++Lr)
            Wmlp[(((size_t)(br * 3 + Lr)) * 256 + o) * 256 + t] =
                f2h(W[(size_t)Lr * 256 * 256 + (size_t)t * 256 + o]);
    } else { // z == 7: fph row o
        for (int i = t; i < FPDP; i += 256) {
            float v = (i < FPD) ? fp[(size_t)o * FPD + i] : 0.f;
            fph[(size_t)o * FPDP + i] = f2h(v);
        }
    }
}

// ---------------------------------------------------------------------------
// fp chain fused (MFMA): layer1 tile -> LDS -> layer2. grid (2), block 256.
__global__ __launch_bounds__(256)
void fp12_mfma(const u16* __restrict__ fph, const u16* __restrict__ W1t,
               const float* __restrict__ b1, const u16* __restrict__ W2t,
               const float* __restrict__ b2, float* __restrict__ FP2,
               u16* __restrict__ FP2h)
{
    __shared__ u16 As[128 * 40];
    __shared__ u16 Bs[128 * 40];
    __shared__ u16 Xs[128 * 136];   // FP1 tile (stride 136: 16B-aligned rows)
    int mt = blockIdx.x;
    const u16* Ap = fph + (size_t)(mt * 128) * FPDP;

    int t = threadIdx.x;
    int l = t & 63, wid = t >> 6;
    int rb = (wid >> 1) * 64, cb = (wid & 1) * 64;
    int ln = l & 15, q = l >> 4;

    {
        f32x4 acc[4][4] = {};
        for (int kt = 0; kt < FPDP / 32; ++kt) {
            #pragma unroll
            for (int i = 0; i < 2; ++i) {
                int id = t + i * 256;
                int row = id >> 2, qh = id & 3;
                *(uint4*)&As[row * 40 + qh * 8] =
                    *(const uint4*)(Ap + (size_t)row * FPDP + kt * 32 + qh * 8);
                *(uint4*)&Bs[row * 40 + qh * 8] =
                    *(const uint4*)(W1t + (size_t)row * FPDP + kt * 32 + qh * 8);
            }
            __syncthreads();
            f16x8 af[4], bfr[4];
            #pragma unroll
            for (int fr = 0; fr < 4; ++fr)
                af[fr] = *(const f16x8*)&As[(rb + fr * 16 + ln) * 40 + q * 8];
            #pragma unroll
            for (int fc = 0; fc < 4; ++fc)
                bfr[fc] = *(const f16x8*)&Bs[(cb + fc * 16 + ln) * 40 + q * 8];
            #pragma unroll
            for (int fr = 0; fr < 4; ++fr)
                #pragma unroll
                for (int fc = 0; fc < 4; ++fc)
                    acc[fr][fc] = __builtin_amdgcn_mfma_f32_16x16x32_f16(
                        af[fr], bfr[fc], acc[fr][fc], 0, 0, 0);
            __syncthreads();
        }
        #pragma unroll
        for (int fr = 0; fr < 4; ++fr)
            #pragma unroll
            for (int fc = 0; fc < 4; ++fc) {
                int d = cb + fc * 16 + ln;
                float bv = b1[d];
                #pragma unroll
                for (int r = 0; r < 4; ++r) {
                    int m = rb + fr * 16 + q * 4 + r;
                    Xs[m * 136 + d] = f2h(fmaxf(acc[fr][fc][r] + bv, 0.f));
                }
            }
    }
    // layer 2: A from Xs
    f32x4 acc[4][4] = {};
    for (int kt = 0; kt < 4; ++kt) {
        __syncthreads();
        #pragma unroll
        for (int i = 0; i < 2; ++i) {
            int id = t + i * 256;
            int row = id >> 2, qh = id & 3;
            *(uint4*)&Bs[row * 40 + qh * 8] =
                *(const uint4*)(W2t + (size_t)row * 128 + kt * 32 + qh * 8);
        }
        __syncthreads();
        f16x8 af[4], bfr[4];
        #pragma unroll
        for (int fr = 0; fr < 4; ++fr)
            af[fr] = *(const f16x8*)&Xs[(rb + fr * 16 + ln) * 136 + kt * 32 + q * 8];
        #pragma unroll
        for (int fc = 0; fc < 4; ++fc)
            bfr[fc] = *(const f16x8*)&Bs[(cb + fc * 16 + ln) * 40 + q * 8];
        #pragma unroll
        for (int fr = 0; fr < 4; ++fr)
            #pragma unroll
            for (int fc = 0; fc < 4; ++fc)
                acc[fr][fc] = __builtin_amdgcn_mfma_f32_16x16x32_f16(
                    af[fr], bfr[fc], acc[fr][fc], 0, 0, 0);
    }
    #pragma unroll
    for (int fr = 0; fr < 4; ++fr)
        #pragma unroll
        for (int fc = 0; fc < 4; ++fc) {
            int d = cb + fc * 16 + ln;
            float bv = b2[d];
            #pragma unroll
            for (int r = 0; r < 4; ++r) {
                int m = rb + fr * 16 + q * 4 + r;
                float val = fmaxf(acc[fr][fc][r] + bv, 0.f);
                FP2 [(size_t)(mt * 128 + m) * 128 + d] = val;
                FP2h[(size_t)(mt * 128 + m) * 128 + d] = f2h(val);
            }
        }
}

// ---------------------------------------------------------------------------
// HS12 tables (MFMA): HS12[r][br*128+d] = fp16(relu(emb[r]@pW_br + b_br[d]))
__global__ __launch_bounds__(256)
void hs12_mfma(const float* __restrict__ emb, const u16* __restrict__ pWt12,
               const float* __restrict__ ba, const float* __restrict__ bb_,
               u16* __restrict__ HS12)
{
    __shared__ u16 As[128 * 40];
    __shared__ u16 Bs[128 * 40];
    int ft = blockIdx.x, br = blockIdx.y;
    const u16* Bp = pWt12 + (size_t)br * 128 * 128;
    const float* bias = br ? bb_ : ba;
    int r0 = ft * 128;

    int t = threadIdx.x;
    int l = t & 63, wid = t >> 6;
    int rb = (wid >> 1) * 64, cb = (wid & 1) * 64;
    int ln = l & 15, q = l >> 4;

    f32x4 acc[4][4] = {};

    for (int kt = 0; kt < 4; ++kt) {
        #pragma unroll
        for (int i = 0; i < 4; ++i) {
            int id = t + i * 256;
            int row = id >> 3, qf = id & 7;
            int r = r0 + row;
            float4 v = make_float4(0.f, 0.f, 0.f, 0.f);
            if (r < NWORD) v = *(const float4*)(emb + (size_t)r * 128 + kt * 32 + qf * 4);
            u32 p0 = (u32)f2h(v.x) | ((u32)f2h(v.y) << 16);
            u32 p1 = (u32)f2h(v.z) | ((u32)f2h(v.w) << 16);
            u32* dst = (u32*)&As[row * 40 + qf * 4];
            dst[0] = p0; dst[1] = p1;
        }
        #pragma unroll
        for (int i = 0; i < 2; ++i) {
            int id = t + i * 256;
            int row = id >> 2, qh = id & 3;
            *(uint4*)&Bs[row * 40 + qh * 8] =
                *(const uint4*)(Bp + (size_t)row * 128 + kt * 32 + qh * 8);
        }
        __syncthreads();
        f16x8 af[4], bfr[4];
        #pragma unroll
        for (int fr = 0; fr < 4; ++fr)
            af[fr] = *(const f16x8*)&As[(rb + fr * 16 + ln) * 40 + q * 8];
        #pragma unroll
        for (int fc = 0; fc < 4; ++fc)
            bfr[fc] = *(const f16x8*)&Bs[(cb + fc * 16 + ln) * 40 + q * 8];
        #pragma unroll
        for (int fr = 0; fr < 4; ++fr)
            #pragma unroll
            for (int fc = 0; fc < 4; ++fc)
                acc[fr][fc] = __builtin_amdgcn_mfma_f32_16x16x32_f16(
                    af[fr], bfr[fc], acc[fr][fc], 0, 0, 0);
        __syncthreads();
    }
    #pragma unroll
    for (int fr = 0; fr < 4; ++fr)
        #pragma unroll
        for (int fc = 0; fc < 4; ++fc) {
            int d = cb + fc * 16 + ln;
            float bv = bias[d];
            #pragma unroll
            for (int r = 0; r < 4; ++r) {
                int m = rb + fr * 16 + q * 4 + r;
                int rr = r0 + m;
                if (rr < NWORD)
                    HS12[(size_t)rr * 256 + br * 128 + d] = f2h(fmaxf(acc[fr][fc][r] + bv, 0.f));
            }
        }
}

// ---------------------------------------------------------------------------
// gA layer 1 (MFMA)
__global__ __launch_bounds__(256)
void gA_mfma(const u16* __restrict__ Agr, const u16* __restrict__ Htr,
             u16* __restrict__ AV, int b0, int htStride, int fpMul, int Fvalid)
{
    __shared__ u16 As[128 * 40];
    __shared__ u16 Bs[128 * 40];
    int ft = blockIdx.x, c = blockIdx.y, bl = blockIdx.z;
    int b = b0 + bl;
    const u16* Ap = Agr + ((size_t)b * AC + c) * (NN * NN);
    const u16* Bp = Htr + (size_t)b * htStride + ft * (128 * 128);
    u16* Cp = AV + (size_t)bl * (NN * KB) + c * fpMul + ft * 128;

    int t = threadIdx.x;
    int l = t & 63, wid = t >> 6;
    int rb = (wid >> 1) * 64, cb = (wid & 1) * 64;
    int ln = l & 15, q = l >> 4;

    f32x4 acc[4][4] = {};

    for (int kt = 0; kt < 4; ++kt) {
        #pragma unroll
        for (int i = 0; i < 2; ++i) {
            int id = t + i * 256;
            int row = id >> 2, qh = id & 3;
            *(uint4*)&As[row * 40 + qh * 8] =
                *(const uint4*)(Ap + (size_t)row * NN + kt * 32 + qh * 8);
        }
        #pragma unroll
        for (int i = 0; i < 2; ++i) {
            int id = t + i * 256;
            int row = id >> 2, qh = id & 3;
            uint4 v = make_uint4(0, 0, 0, 0);
            if (row < Fvalid) v = *(const uint4*)(Bp + (size_t)row * 128 + kt * 32 + qh * 8);
            *(uint4*)&Bs[row * 40 + qh * 8] = v;
        }
        __syncthreads();
        f16x8 af[4], bfr[4];
        #pragma unroll
        for (int fr = 0; fr < 4; ++fr)
            af[fr] = *(const f16x8*)&As[(rb + fr * 16 + ln) * 40 + q * 8];
        #pragma unroll
        for (int fc = 0; fc < 4; ++fc)
            bfr[fc] = *(const f16x8*)&Bs[(cb + fc * 16 + ln) * 40 + q * 8];
        #pragma unroll
        for (int fr = 0; fr < 4; ++fr)
            #pragma unroll
            for (int fc = 0; fc < 4; ++fc)
                acc[fr][fc] = __builtin_amdgcn_mfma_f32_16x16x32_f16(
                    af[fr], bfr[fc], acc[fr][fc], 0, 0, 0);
        __syncthreads();
    }
    #pragma unroll
    for (int fr = 0; fr < 4; ++fr) {
        #pragma unroll
        for (int fc = 0; fc < 4; ++fc) {
            int fcol = cb + fc * 16 + ln;
            if (fcol < Fvalid) {
                #pragma unroll
                for (int r = 0; r < 4; ++r) {
                    int n = rb + fr * 16 + q * 4 + r;
                    Cp[(size_t)n * KB + fcol] = f2h_sat(acc[fr][fc][r] * SC);
                }
            }
        }
    }
}

// ---------------------------------------------------------------------------
// gA2 (layers 2/3): full A-tile staged once in LDS; both f-tiles per block.
__global__ __launch_bounds__(256)
void gA2_mfma(const u16* __restrict__ Agr, const u16* __restrict__ Htr,
              u16* __restrict__ AV, int b0)
{
    __shared__ u16 As[4][128 * 40];
    __shared__ u16 Bs[128 * 40];
    int c = blockIdx.x, bl = blockIdx.y;
    int b = b0 + bl;
    const u16* Ap = Agr + ((size_t)b * AC + c) * (NN * NN);
    u16* Cp0 = AV + (size_t)bl * (NN * KB) + c * 256;

    int t = threadIdx.x;
    int l = t & 63, wid = t >> 6;
    int rb = (wid >> 1) * 64, cb = (wid & 1) * 64;
    int ln = l & 15, q = l >> 4;

    #pragma unroll
    for (int i = 0; i < 8; ++i) {
        int id = t + i * 256;
        int row = id >> 4, kq = id & 15;
        int kt = kq >> 2, qh = kq & 3;
        *(uint4*)&As[kt][row * 40 + qh * 8] =
            *(const uint4*)(Ap + (size_t)row * NN + kt * 32 + qh * 8);
    }

    for (int ft = 0; ft < 2; ++ft) {
        const u16* Bp = Htr + (size_t)b * (HID * NN) + ft * (128 * 128);
        f32x4 acc[4][4] = {};
        for (int kt = 0; kt < 4; ++kt) {
            __syncthreads();
            #pragma unroll
            for (int i = 0; i < 2; ++i) {
                int id = t + i * 256;
                int row = id >> 2, qh = id & 3;
                *(uint4*)&Bs[row * 40 + qh * 8] =
                    *(const uint4*)(Bp + (size_t)row * 128 + kt * 32 + qh * 8);
            }
            __syncthreads();
            f16x8 af[4], bfr[4];
            #pragma unroll
            for (int fr = 0; fr < 4; ++fr)
                af[fr] = *(const f16x8*)&As[kt][(rb + fr * 16 + ln) * 40 + q * 8];
            #pragma unroll
            for (int fc = 0; fc < 4; ++fc)
                bfr[fc] = *(const f16x8*)&Bs[(cb + fc * 16 + ln) * 40 + q * 8];
            #pragma unroll
            for (int fr = 0; fr < 4; ++fr)
                #pragma unroll
                for (int fc = 0; fc < 4; ++fc)
                    acc[fr][fc] = __builtin_amdgcn_mfma_f32_16x16x32_f16(
                        af[fr], bfr[fc], acc[fr][fc], 0, 0, 0);
        }
        #pragma unroll
        for (int fr = 0; fr < 4; ++fr)
            #pragma unroll
            for (int fc = 0; fc < 4; ++fc) {
                int fcol = ft * 128 + cb + fc * 16 + ln;
                #pragma unroll
                for (int r = 0; r < 4; ++r) {
                    int n = rb + fr * 16 + q * 4 + r;
                    Cp0[(size_t)n * KB + fcol] = f2h_sat(acc[fr][fc][r] * SC);
                }
            }
    }
}

// ---------------------------------------------------------------------------
// gB (MFMA): mode 0 -> DIRECT transposed packed store to Ht; mode 1 -> H3h.
__global__ __launch_bounds__(256)
void gB_mfma(const u16* __restrict__ AV, const u16* __restrict__ Wt,
             const float* __restrict__ bias, u16* __restrict__ Hout,
             int b0, int kTiles, int Ks, int mode)
{
    __shared__ u16 As[128 * 40];
    __shared__ u16 Bs[128 * 40];
    int ot = blockIdx.x, bl = blockIdx.y;
    int b = b0 + bl;
    const u16* Ap = AV + (size_t)bl * (NN * KB);
    const u16* Bp = Wt + (size_t)ot * 128 * Ks;

    int t = threadIdx.x;
    int l = t & 63, wid = t >> 6;
    int rb = (wid >> 1) * 64, cb = (wid & 1) * 64;
    int ln = l & 15, q = l >> 4;

    f32x4 acc[4][4] = {};

    for (int kt = 0; kt < kTiles; ++kt) {
        #pragma unroll
        for (int i = 0; i < 2; ++i) {
            int id = t + i * 256;
            int row = id >> 2, qh = id & 3;
            *(uint4*)&As[row * 40 + qh * 8] =
                *(const uint4*)(Ap + (size_t)row * KB + kt * 32 + qh * 8);
            *(uint4*)&Bs[row * 40 + qh * 8] =
                *(const uint4*)(Bp + (size_t)row * Ks + kt * 32 + qh * 8);
        }
        __syncthreads();
        f16x8 af[4], bfr[4];
        #pragma unroll
        for (int fr = 0; fr < 4; ++fr)
            af[fr] = *(const f16x8*)&As[(rb + fr * 16 + ln) * 40 + q * 8];
        #pragma unroll
        for (int fc = 0; fc < 4; ++fc)
            bfr[fc] = *(const f16x8*)&Bs[(cb + fc * 16 + ln) * 40 + q * 8];
        #pragma unroll
        for (int fr = 0; fr < 4; ++fr)
            #pragma unroll
            for (int fc = 0; fc < 4; ++fc)
                acc[fr][fc] = __builtin_amdgcn_mfma_f32_16x16x32_f16(
                    af[fr], bfr[fc], acc[fr][fc], 0, 0, 0);
        __syncthreads();
    }
    if (mode == 0) {
        #pragma unroll
        for (int fr = 0; fr < 4; ++fr)
            #pragma unroll
            for (int fc = 0; fc < 4; ++fc) {
                int oc = cb + fc * 16 + ln;
                float bv = bias[ot * 128 + oc];
                int n0 = rb + fr * 16 + q * 4;
                u16 v0 = f2h_sat(fmaxf(acc[fr][fc][0] * USC + bv, 0.f));
                u16 v1 = f2h_sat(fmaxf(acc[fr][fc][1] * USC + bv, 0.f));
                u16 v2 = f2h_sat(fmaxf(acc[fr][fc][2] * USC + bv, 0.f));
                u16 v3 = f2h_sat(fmaxf(acc[fr][fc][3] * USC + bv, 0.f));
                uint2 pk = make_uint2((u32)v0 | ((u32)v1 << 16),
                                      (u32)v2 | ((u32)v3 << 16));
                *(uint2*)(Hout + ((size_t)b * HID + ot * 128 + oc) * NN + n0) = pk;
            }
    } else {
        #pragma unroll
        for (int fr = 0; fr < 4; ++fr)
            #pragma unroll
            for (int fc = 0; fc < 4; ++fc) {
                int oc = cb + fc * 16 + ln;
                float bv = bias[ot * 128 + oc];
                #pragma unroll
                for (int r = 0; r < 4; ++r) {
                    int n = rb + fr * 16 + q * 4 + r;
                    float val = fmaxf(acc[fr][fc][r] * USC + bv, 0.f);
                    Hout[((size_t)b * NN + n) * HID + ot * 128 + oc] = f2h_sat(val * SC);
                }
            }
    }
}

// ---------------------------------------------------------------------------
// Masked multi-head attention pooling. H3h fp16 scaled 1/16; single-pass.
__global__ __launch_bounds__(256)
void pool_kernel(const u16* __restrict__ H3h,
                 const float* __restrict__ attW,
                 const int* __restrict__ msz,
                 float* __restrict__ pooled)
{
    int b = blockIdx.x, t = threadIdx.x;
    __shared__ u16  sTh[128][264];
    __shared__ float sW[HID * NHEAD];
    __shared__ float sS[NN * NHEAD];
    __shared__ float sP[16][NHEAD][2];
    for (int i = t; i < HID * NHEAD; i += 256) sW[i] = attW[i];
    const u16* Hb = H3h + (size_t)b * NN * HID;
    for (int i = t; i < 128 * 32; i += 256) {
        int row = i >> 5, fq = (i & 31) * 8;
        *(uint4*)&sTh[row][fq] = *(const uint4*)(Hb + (size_t)row * HID + fq);
    }
    __syncthreads();
    for (int n0 = 0; n0 < NN; n0 += 16) {
        int nl = t >> 4, h = (t >> 1) & 7, fh = t & 1;
        float s = 0.f;
        for (int f = fh * 128; f < fh * 128 + 128; ++f)
            s += h2f(sTh[n0 + nl][f]) * sW[f * NHEAD + h];
        sP[nl][h][fh] = s;
        __syncthreads();
        if (t < 128) {
            int n2 = t >> 3, h2 = t & 7;
            sS[(n0 + n2) * NHEAD + h2] = USC * (sP[n2][h2][0] + sP[n2][h2][1]);
        }
        __syncthreads();
    }
    int ms = msz[b];
    int h = t >> 5, ln = t & 31;
    float mx = -1e9f;
    for (int n = ln; n < NN; n += 32) {
        float s = (n < ms) ? sS[n * NHEAD + h] : -1e9f;
        mx = fmaxf(mx, s);
    }
    #pragma unroll
    for (int off = 16; off; off >>= 1) mx = fmaxf(mx, __shfl_xor(mx, off, 32));
    float sum = 0.f;
    for (int n = ln; n < NN; n += 32) {
        float s = (n < ms) ? sS[n * NHEAD + h] : -1e9f;
        sum += expf(s - mx);
    }
    #pragma unroll
    for (int off = 16; off; off >>= 1) sum += __shfl_xor(sum, off, 32);
    float inv = 1.f / sum;
    for (int n = ln; n < NN; n += 32) {
        float s = (n < ms) ? sS[n * NHEAD + h] : -1e9f;
        sS[n * NHEAD + h] = expf(s - mx) * inv;
    }
    __syncthreads();
    float accp[NHEAD] = {};
    for (int n = 0; n < NN; ++n) {
        float hv = h2f(sTh[n][t]);
        #pragma unroll
        for (int hh = 0; hh < NHEAD; ++hh) accp[hh] += sS[n * NHEAD + hh] * hv;
    }
    #pragma unroll
    for (int hh = 0; hh < NHEAD; ++hh)
        pooled[(size_t)b * (HID * NHEAD) + hh * HID + t] = USC * accp[hh];
}

// ---------------------------------------------------------------------------
// Readout, k-split
__global__ __launch_bounds__(128)
void readout_part(const float* __restrict__ pooled,
                  const float* __restrict__ roW,
                  float* __restrict__ Rp)
{
    int b = blockIdx.x, s = blockIdx.y, t = threadIdx.x;
    __shared__ float sx[256];
    const float* sp = pooled + (size_t)b * (HID * NHEAD) + s * 256;
    sx[t] = sp[t];
    sx[t + 128] = sp[t + 128];
    __syncthreads();
    float acc = 0.f;
    const float* W = roW + (size_t)(s * 256) * DIM + t;
    for (int k = 0; k < 256; ++k) acc += sx[k] * W[(size_t)k * DIM];
    Rp[((size_t)s * BB + b) * DIM + t] = acc;
}

__global__ __launch_bounds__(128)
void readout_merge(const float* __restrict__ Rp,
                   const float* __restrict__ rob,
                   float* __restrict__ Vr, u16* __restrict__ Vrh)
{
    int b = blockIdx.x, t = threadIdx.x;
    float a = rob[t];
    #pragma unroll
    for (int s = 0; s < 8; ++s) a += Rp[((size_t)s * BB + b) * DIM + t];
    float v = fmaxf(a, 0.f);
    Vr [(size_t)b * DIM + t] = v;
    Vrh[(size_t)b * DIM + t] = f2h_sat(v * SC);   // scaled 1/16
}

// ---------------------------------------------------------------------------
// atth (MFMA): h_br = relu(X_br @ W_br + b_br) -> fp16 out. grid (2 mt, 2 br).
__global__ __launch_bounds__(256)
void atth_mfma(const u16* __restrict__ FP2h, const u16* __restrict__ VRh,
               const u16* __restrict__ mWt12,
               const float* __restrict__ mfpb, const float* __restrict__ mvb,
               u16* __restrict__ h1h, u16* __restrict__ h2h)
{
    __shared__ u16 As[128 * 40];
    __shared__ u16 Bs[128 * 40];
    int mt = blockIdx.x, br = blockIdx.y;
    const u16* Ap = (br ? VRh : FP2h) + (size_t)(mt * 128) * 128;
    const u16* Bp = mWt12 + (size_t)br * 128 * 128;
    const float* bias = br ? mvb : mfpb;
    float unsc = br ? USC : 1.f;
    u16* out = br ? h2h : h1h;

    int t = threadIdx.x;
    int l = t & 63, wid = t >> 6;
    int rb = (wid >> 1) * 64, cb = (wid & 1) * 64;
    int ln = l & 15, q = l >> 4;

    f32x4 acc[4][4] = {};

    for (int kt = 0; kt < 4; ++kt) {
        #pragma unroll
        for (int i = 0; i < 2; ++i) {
            int id = t + i * 256;
            int row = id >> 2, qh = id & 3;
            *(uint4*)&As[row * 40 + qh * 8] =
                *(const uint4*)(Ap + (size_t)row * 128 + kt * 32 + qh * 8);
            *(uint4*)&Bs[row * 40 + qh * 8] =
                *(const uint4*)(Bp + (size_t)row * 128 + kt * 32 + qh * 8);
        }
        __syncthreads();
        f16x8 af[4], bfr[4];
        #pragma unroll
        for (int fr = 0; fr < 4; ++fr)
            af[fr] = *(const f16x8*)&As[(rb + fr * 16 + ln) * 40 + q * 8];
        #pragma unroll
        for (int fc = 0; fc < 4; ++fc)
            bfr[fc] = *(const f16x8*)&Bs[(cb + fc * 16 + ln) * 40 + q * 8];
        #pragma unroll
        for (int fr = 0; fr < 4; ++fr)
            #pragma unroll
            for (int fc = 0; fc < 4; ++fc)
                acc[fr][fc] = __builtin_amdgcn_mfma_f32_16x16x32_f16(
                    af[fr], bfr[fc], acc[fr][fc], 0, 0, 0);
        __syncthreads();
    }
    #pragma unroll
    for (int fr = 0; fr < 4; ++fr)
        #pragma unroll
        for (int fc = 0; fc < 4; ++fc) {
            int d = cb + fc * 16 + ln;
            float bv = bias[d];
            #pragma unroll
            for (int r = 0; r < 4; ++r) {
                int m = rb + fr * 16 + q * 4 + r;
                out[(size_t)(mt * 128 + m) * 128 + d] =
                    f2h_sat(fmaxf(acc[fr][fc][r] * unsc + bv, 0.f));
            }
        }
}

// ---------------------------------------------------------------------------
// Cross-attn partial scan: fdot2 dot products, packed-fp16 max, fast tanh.
__global__ __launch_bounds__(256)
void cross_part_kernel(const int* __restrict__ seq,
                       const u16* __restrict__ HS12,
                       const u16* __restrict__ h1h, const u16* __restrict__ h2h,
                       float* __restrict__ Pc)   // [8][B][2][128]
{
    int b = blockIdx.x, s = blockIdx.y, t = threadIdx.x;
    int g = t >> 4, gl = t & 15;
    int d0 = gl * 8;
    f16x8 h1 = *(const f16x8*)(h1h + (size_t)b * DIM + d0);
    f16x8 h2 = *(const f16x8*)(h2h + (size_t)b * DIM + d0);
    const h2v* h1p = (const h2v*)&h1;
    const h2v* h2p = (const h2v*)&h2;
    h2v m1[4], m2[4];
    _Float16 NEGBIG = (_Float16)(-65504.f);
    #pragma unroll
    for (int k = 0; k < 4; ++k) { m1[k] = (h2v){NEGBIG, NEGBIG}; m2[k] = (h2v){NEGBIG, NEGBIG}; }
    const int* sq = seq + (size_t)b * LL + s * 256;
    for (int it = 0; it < 16; ++it) {
        int tok = sq[g + 16 * it];
        const u16* r12 = HS12 + (size_t)tok * 256 + d0;
        f16x8 va = *(const f16x8*)(r12);
        f16x8 vb = *(const f16x8*)(r12 + 128);
        const h2v* vap = (const h2v*)&va;
        const h2v* vbp = (const h2v*)&vb;
        float p1 = 0.f, p2 = 0.f;
        #pragma unroll
        for (int k = 0; k < 4; ++k) {
            p1 = __builtin_amdgcn_fdot2(vap[k], h1p[k], p1, false);
            p2 = __builtin_amdgcn_fdot2(vbp[k], h2p[k], p2, false);
        }
        #pragma unroll
        for (int off = 8; off; off >>= 1) {
            p1 += __shfl_xor(p1, off);
            p2 += __shfl_xor(p2, off);
        }
        float w1 = 1.f - 2.f / (__expf(2.f * p1) + 1.f);
        float w2 = 1.f - 2.f / (__expf(2.f * p2) + 1.f);
        _Float16 w1s = (_Float16)w1, w2s = (_Float16)w2;
        h2v w1p = (h2v){w1s, w1s}, w2p = (h2v){w2s, w2s};
        #pragma unroll
        for (int k = 0; k < 4; ++k) {
            h2v pr1 = w1p * vap[k];
            h2v pr2 = w2p * vbp[k];
            m1[k] = (h2v){ m1[k][0] > pr1[0] ? m1[k][0] : pr1[0],
                           m1[k][1] > pr1[1] ? m1[k][1] : pr1[1] };
            m2[k] = (h2v){ m2[k][0] > pr2[0] ? m2[k][0] : pr2[0],
                           m2[k][1] > pr2[1] ? m2[k][1] : pr2[1] };
        }
    }
    __shared__ float red[16][2][DIM];
    #pragma unroll
    for (int k = 0; k < 4; ++k) {
        red[g][0][d0 + 2 * k]     = (float)m1[k][0];
        red[g][0][d0 + 2 * k + 1] = (float)m1[k][1];
        red[g][1][d0 + 2 * k]     = (float)m2[k][0];
        red[g][1][d0 + 2 * k + 1] = (float)m2[k][1];
    }
    __syncthreads();
    int tb = t >> 7, d = t & 127;
    float mx = red[0][tb][d];
    #pragma unroll
    for (int gg = 1; gg < 16; ++gg) mx = fmaxf(mx, red[gg][tb][d]);
    Pc[(((size_t)s * BB + b) * 2 + tb) * DIM + d] = mx;
}

// ---------------------------------------------------------------------------
// prepX: build MLP input (merges cross merge). Xh [br][256][256], scaled 1/16.
__global__ __launch_bounds__(256)
void prepX_kernel(const float* __restrict__ FP2, const float* __restrict__ VR,
                  const float* __restrict__ Pc, u16* __restrict__ Xh)
{
    int b = blockIdx.x, br = blockIdx.y, t = threadIdx.x;
    float v;
    if (t < 128) {
        v = (br ? VR : FP2)[(size_t)b * 128 + t];
    } else {
        int d = t - 128;
        float m = -INFINITY;
        #pragma unroll
        for (int s = 0; s < 8; ++s)
            m = fmaxf(m, Pc[(((size_t)s * BB + b) * 2 + br) * DIM + d]);
        v = m;
    }
    Xh[((size_t)br * BB + b) * 256 + t] = f2h_sat(v * SC);
}

// one MLP layer: Y = relu(X@W+b), in/out scaled 1/16. grid (2 mt, 2 ot, 2 br).
__global__ __launch_bounds__(256)
void mlpL_mfma(const u16* __restrict__ X, const u16* __restrict__ Wmlp,
               const float* __restrict__ m1b, const float* __restrict__ m2b,
               int Lr, u16* __restrict__ Y)
{
    __shared__ u16 As[128 * 40];
    __shared__ u16 Bs[128 * 40];
    int mt = blockIdx.x, ot = blockIdx.y, br = blockIdx.z;
    const u16* Ap = X + ((size_t)br * BB + mt * 128) * 256;
    const u16* Bp = Wmlp + (((size_t)(br * 3 + Lr)) * 256 + ot * 128) * 256;
    const float* bias = (br ? m2b : m1b) + (size_t)Lr * 256 + ot * 128;

    int t = threadIdx.x;
    int l = t & 63, wid = t >> 6;
    int rb = (wid >> 1) * 64, cb = (wid & 1) * 64;
    int ln = l & 15, q = l >> 4;

    f32x4 acc[4][4] = {};

    for (int kt = 0; kt < 8; ++kt) {
        #pragma unroll
        for (int i = 0; i < 2; ++i) {
            int id = t + i * 256;
            int row = id >> 2, qh = id & 3;
            *(uint4*)&As[row * 40 + qh * 8] =
                *(const uint4*)(Ap + (size_t)row * 256 + kt * 32 + qh * 8);
            *(uint4*)&Bs[row * 40 + qh * 8] =
                *(const uint4*)(Bp + (size_t)row * 256 + kt * 32 + qh * 8);
        }
        __syncthreads();
        f16x8 af[4], bfr[4];
        #pragma unroll
        for (int fr = 0; fr < 4; ++fr)
            af[fr] = *(const f16x8*)&As[(rb + fr * 16 + ln) * 40 + q * 8];
        #pragma unroll
        for (int fc = 0; fc < 4; ++fc)
            bfr[fc] = *(const f16x8*)&Bs[(cb + fc * 16 + ln) * 40 + q * 8];
        #pragma unroll
        for (int fr = 0; fr < 4; ++fr)
            #pragma unroll
            for (int fc = 0; fc < 4; ++fc)
                acc[fr][fc] = __builtin_amdgcn_mfma_f32_16x16x32_f16(
                    af[fr], bfr[fc], acc[fr][fc], 0, 0, 0);
        __syncthreads();
    }
    #pragma unroll
    for (int fr = 0; fr < 4; ++fr)
        #pragma unroll
        for (int fc = 0; fc < 4; ++fc) {
            int oc = cb + fc * 16 + ln;
            float bv = bias[oc] * SC;
            #pragma unroll
            for (int r = 0; r < 4; ++r) {
                int m = rb + fr * 16 + q * 4 + r;
                Y[((size_t)br * BB + (mt * 128 + m)) * 256 + ot * 128 + oc] =
                    f2h_sat(fmaxf(acc[fr][fc][r] + bv, 0.f));
            }
        }
}

// head + outputs. grid (BB), block 256.
__global__ __launch_bounds__(256)
void mlp_out_kernel(const u16* __restrict__ Y,
                    const float* __restrict__ o1W, const float* __restrict__ o1b,
                    const float* __restrict__ o2W, const float* __restrict__ o2b,
                    const int* __restrict__ label,
                    float* __restrict__ dout)
{
    int b = blockIdx.x, t = threadIdx.x;
    __shared__ float pl[2][128];
    const u16* y1 = Y + (size_t)b * 256;
    const u16* y2 = Y + ((size_t)BB + b) * 256;
    int j = t & 1, k2 = t >> 1;
    float p = USC * (h2f(y1[k2])       * o1W[k2 * 2 + j]
                   + h2f(y1[k2 + 128]) * o1W[(k2 + 128) * 2 + j]
                   + h2f(y2[k2])       * o2W[k2 * 2 + j]
                   + h2f(y2[k2 + 128]) * o2W[(k2 + 128) * 2 + j]);
    pl[j][k2] = p;
    __syncthreads();
    for (int s = 64; s > 0; s >>= 1) {
        if (k2 < s) pl[j][k2] += pl[j][k2 + s];
        __syncthreads();
    }
    if (t == 0) {
        float l0 = pl[0][0] + o1b[0] + o2b[0];
        float l1 = pl[1][0] + o1b[1] + o2b[1];
        dout[(size_t)b * 2 + 0] = l0;
        dout[(size_t)b * 2 + 1] = l1;
        dout[2 * BB + b] = (float)label[b];
        dout[3 * BB + b] = (float)((l1 > l0) ? 1 : 0);
        float mx = fmaxf(l0, l1);
        float e0 = expf(l0 - mx), e1 = expf(l1 - mx);
        dout[4 * BB + b] = e1 / (e0 + e1);
    }
}

// ---------------------------------------------------------------------------
extern "C" void kernel_launch(void* const* d_in, const int* in_sizes, int n_in,
                              void* d_out, int out_size, void* d_ws, size_t ws_size,
                              hipStream_t stream)
{
    const float* V    = (const float*)d_in[0];
    const float* A    = (const float*)d_in[1];
    const float* fp   = (const float*)d_in[2];
    const int*   msz  = (const int*)  d_in[3];
    const int*   seq  = (const int*)  d_in[4];
    const int*   lab  = (const int*)  d_in[5];
    const float* gcW1 = (const float*)d_in[6];  const float* gcb1 = (const float*)d_in[7];
    const float* gcW2 = (const float*)d_in[8];  const float* gcb2 = (const float*)d_in[9];
    const float* gcW3 = (const float*)d_in[10]; const float* gcb3 = (const float*)d_in[11];
    const float* fpW1 = (const float*)d_in[12]; const float* fpb1 = (const float*)d_in[13];
    const float* fpW2 = (const float*)d_in[14]; const float* fpb2 = (const float*)d_in[15];
    const float* attW = (const float*)d_in[16];
    const float* roW  = (const float*)d_in[17]; const float* rob  = (const float*)d_in[18];
    const float* emb  = (const float*)d_in[19];
    const float* mfpW = (const float*)d_in[20]; const float* mfpb = (const float*)d_in[21];
    const float* pfpW = (const float*)d_in[22]; const float* pfpb = (const float*)d_in[23];
    const float* mvW  = (const float*)d_in[24]; const float* mvb  = (const float*)d_in[25];
    const float* pvW  = (const float*)d_in[26]; const float* pvb  = (const float*)d_in[27];
    const float* m1W  = (const float*)d_in[28]; const float* m1b  = (const float*)d_in[29];
    const float* m2W  = (const float*)d_in[30]; const float* m2b  = (const float*)d_in[31];
    const float* o1W  = (const float*)d_in[32]; const float* o1b  = (const float*)d_in[33];
    const float* o2W  = (const float*)d_in[34]; const float* o2b  = (const float*)d_in[35];
    float* dout = (float*)d_out;

    // workspace layout
    char* ws = (char*)d_ws;
    size_t off = 0;
    auto alloc = [&](size_t bytes) -> char* {
        char* p = ws + off;
        off += (bytes + 255) & ~(size_t)255;
        return p;
    };
    u16*   Ah    = (u16*)  alloc((size_t)BB * AC * NN * NN * 2);   // 25.2 MB
    u16*   Vt    = (u16*)  alloc((size_t)BB * 80 * 128 * 2);       // 5.24 MB
    u16*   Wt1   = (u16*)  alloc((size_t)256 * 256 * 2);
    u16*   Wt2   = (u16*)  alloc((size_t)256 * KB * 2);
    u16*   Wt3   = (u16*)  alloc((size_t)256 * KB * 2);
    u16*   Ht    = (u16*)  alloc((size_t)BB * HID * NN * 2);       // 16.8 MB
    u16*   H3h   = (u16*)  alloc((size_t)BB * NN * HID * 2);       // 16.8 MB (fp16, 1/16)
    u16*   fph   = (u16*)  alloc((size_t)BB * FPDP * 2);
    u16*   W1t   = (u16*)  alloc((size_t)DIM * FPDP * 2);
    u16*   W2t   = (u16*)  alloc((size_t)DIM * DIM * 2);
    float* FP2   = (float*)alloc((size_t)BB * DIM * 4);
    u16*   FP2h  = (u16*)  alloc((size_t)BB * DIM * 2);
    u16*   pWt12 = (u16*)  alloc((size_t)2 * 128 * 128 * 2);
    u16*   mWt12 = (u16*)  alloc((size_t)2 * 128 * 128 * 2);
    u16*   HS12  = (u16*)  alloc((size_t)NWP * 256 * 2);           // 4.45 MB
    float* PO    = (float*)alloc((size_t)BB * HID * NHEAD * 4);
    float* VR    = (float*)alloc((size_t)BB * DIM * 4);
    u16*   VRh   = (u16*)  alloc((size_t)BB * DIM * 2);
    u16*   h1h   = (u16*)  alloc((size_t)BB * DIM * 2);
    u16*   h2h   = (u16*)  alloc((size_t)BB * DIM * 2);
    float* Pc    = (float*)alloc((size_t)8 * BB * 2 * DIM * 4);
    float* Rp    = (float*)alloc((size_t)8 * BB * DIM * 4);
    u16*   Wmlp  = (u16*)  alloc((size_t)2 * 3 * 256 * 256 * 2);   // 786 KB
    u16*   Xa    = (u16*)  alloc((size_t)2 * BB * 256 * 2);        // 256 KB
    u16*   Xb    = (u16*)  alloc((size_t)2 * BB * 256 * 2);
    size_t fixedBytes = off;

    // AV tier (fp16, per-b 128*768*2 = 196608 B)
    int CB = 8;
    size_t perB = (size_t)NN * KB * 2;
    {
        const int tiers[] = {256, 128, 64, 32, 16, 8, 4, 2, 1};
        for (int i = 0; i < 9; ++i)
            if (fixedBytes + (size_t)tiers[i] * perB <= ws_size) { CB = tiers[i]; break; }
    }
    u16* AV = (u16*)(ws + fixedBytes);

    // prep + independent front-end
    prepA_kernel<<<BB * AC, 256, 0, stream>>>(A, Ah);
    prepVt_kernel<<<BB, 256, 0, stream>>>(V, Vt);
    prepAllW_kernel<<<dim3(256, 8), 256, 0, stream>>>(
        gcW1, gcW2, gcW3, fpW1, fpW2, pfpW, pvW, mfpW, mvW, m1W, m2W, fp,
        Wt1, Wt2, Wt3, W1t, W2t, pWt12, mWt12, Wmlp, fph);
    fp12_mfma<<<2, 256, 0, stream>>>(fph, W1t, fpb1, W2t, fpb2, FP2, FP2h);
    hs12_mfma<<<dim3(NWP / 128, 2), 256, 0, stream>>>(emb, pWt12, pfpb, pvb, HS12);

    // GConv layer 1 (F=75 padded to 80; gB writes Ht directly, transposed)
    for (int b0 = 0; b0 < BB; b0 += CB) {
        gA_mfma<<<dim3(1, AC, CB), 256, 0, stream>>>(Ah, Vt, AV, b0, 80 * 128, 80, 80);
        gB_mfma<<<dim3(2, CB), 256, 0, stream>>>(AV, Wt1, gcb1, Ht, b0, 8, 256, 0);
    }
    // layer 2
    for (int b0 = 0; b0 < BB; b0 += CB) {
        gA2_mfma<<<dim3(AC, CB), 256, 0, stream>>>(Ah, Ht, AV, b0);
        gB_mfma<<<dim3(2, CB), 256, 0, stream>>>(AV, Wt2, gcb2, Ht, b0, 24, KB, 0);
    }
    // layer 3 -> H3h fp16 scaled 1/16
    for (int b0 = 0; b0 < BB; b0 += CB) {
        gA2_mfma<<<dim3(AC, CB), 256, 0, stream>>>(Ah, Ht, AV, b0);
        gB_mfma<<<dim3(2, CB), 256, 0, stream>>>(AV, Wt3, gcb3, H3h, b0, 24, KB, 1);
    }

    pool_kernel<<<BB, 256, 0, stream>>>(H3h, attW, msz, PO);
    readout_part<<<dim3(BB, 8), 128, 0, stream>>>(PO, roW, Rp);
    readout_merge<<<BB, 128, 0, stream>>>(Rp, rob, VR, VRh);
    atth_mfma<<<dim3(2, 2), 256, 0, stream>>>(FP2h, VRh, mWt12, mfpb, mvb, h1h, h2h);
    cross_part_kernel<<<dim3(BB, 8), 256, 0, stream>>>(seq, HS12, h1h, h2h, Pc);
    prepX_kernel<<<dim3(BB, 2), 256, 0, stream>>>(FP2, VR, Pc, Xa);
    mlpL_mfma<<<dim3(2, 2, 2), 256, 0, stream>>>(Xa, Wmlp, m1b, m2b, 0, Xb);
    mlpL_mfma<<<dim3(2, 2, 2), 256, 0, stream>>>(Xb, Wmlp, m1b, m2b, 1, Xa);
    mlpL_mfma<<<dim3(2, 2, 2), 256, 0, stream>>>(Xa, Wmlp, m1b, m2b, 2, Xb);
    mlp_out_kernel<<<BB, 256, 0, stream>>>(Xb, o1W, o1b, o2W, o2b, lab, dout);
}